// Round 4
// baseline (454.862 us; speedup 1.0000x reference)
//
#include <hip/hip_runtime.h>

typedef __attribute__((ext_vector_type(8))) short s16x8;            // 8 bf16 (MFMA A/B frag)
typedef __attribute__((ext_vector_type(8))) unsigned short u16x8;   // 16 B vector
typedef __attribute__((ext_vector_type(4))) float f32x4;            // MFMA C/D frag

#define ALPHA_F 0.36787944117144233f
#define BETA_F  0.36787944117144233f
#define OMB_F   0.63212055882855767f   /* 1 - beta */

#define XS_U16   6144   /* one staging buffer: 768 units x 16 B = 12288 B (720 used + 48 slack) */
#define XS_RSTR  576    /* row stride in u16: 18 pos x 32 ci */
#define YS_STRIDE 66    /* epilogue halved: ys[128 pix][66] u16 (64 t + pad), 16896 B */

#define X2_CICSTR 415872u   /* 114*114*32 u16 per (bz,cic) plane */
#define X2_BZSTR  1663488u  /* 4 * X2_CICSTR */

typedef __attribute__((address_space(1))) const unsigned int gu32;
typedef __attribute__((address_space(3))) unsigned int lu32;

__device__ __forceinline__ unsigned short f2bf(float f){
  union { float f; unsigned int u; } v; v.f = f;
  unsigned int u = v.u;
  return (unsigned short)((u + 0x7FFFu + ((u >> 16) & 1u)) >> 16);  // RNE
}
__device__ __forceinline__ float bf2f(unsigned short s){
  union { unsigned int u; float f; } v; v.u = ((unsigned int)s) << 16;
  return v.f;
}

// ---- Kernel 0: W (co,ci,3,3) fp32 -> Wr bf16 [pos9][cic4][co128][cil32] ----
__global__ __launch_bounds__(256) void reorder_w(const float* __restrict__ W,
                                                 unsigned short* __restrict__ Wr){
  int f = blockIdx.x * 256 + threadIdx.x;
  if (f >= 9*128*128) return;
  int cil = f & 31;
  int co  = (f >> 5) & 127;
  int cic = (f >> 12) & 3;
  int pos = f >> 14;
  int ci  = (cic << 5) | cil;
  Wr[f] = f2bf(W[(co*128 + ci)*9 + pos]);
}

// ---- Kernel 0b: x NCHW f32 -> x2[bz][cic][114][114][32] bf16, zero-padded halo.
__global__ __launch_bounds__(256) void convert_x(const float* __restrict__ x,
                                                 unsigned short* __restrict__ x2){
  __shared__ float ls[112*33 + 1];            // ls[w*33 + ci], pad 33 (odd stride)
  const int tid = threadIdx.x;
  const int h = blockIdx.x, cic = blockIdx.y, bz = blockIdx.z;
  const float* src = x + ((size_t)(bz*128 + cic*32))*12544 + (size_t)h*112;
  #pragma unroll
  for (int r = 0; r < 7; ++r){
    int u2 = r*256 + tid;                     // 0..1791 = 32ci * 56 float2
    int ci = u2 / 56, w2 = (u2 - ci*56) << 1;
    float2 v = *(const float2*)(src + (size_t)ci*12544 + w2);
    ls[w2*33 + ci] = v.x;
    ls[(w2+1)*33 + ci] = v.y;
  }
  __syncthreads();
  unsigned short* dst = x2 + (size_t)(bz*4 + cic)*X2_CICSTR + (size_t)(h+1)*(114*32);
  #pragma unroll
  for (int r = 0; r < 7; ++r){
    int u2 = r*256 + tid;                     // 0..1791 = 112pw * 16 pairs
    int pw = u2 >> 4, c2 = (u2 & 15) << 1;
    ushort2 o;
    o.x = f2bf(ls[pw*33 + c2]);
    o.y = f2bf(ls[pw*33 + c2 + 1]);
    *(ushort2*)(dst + (pw+1)*32 + c2) = o;    // contiguous 128 B per wave
  }
  if (tid < 64){
    int cil = tid & 31;
    dst[((tid >> 5) ? 113*32 : 0) + cil] = 0;
  }
  if (h == 0 || h == 111){
    unsigned short* brow = x2 + (size_t)(bz*4 + cic)*X2_CICSTR
                              + (size_t)(h == 0 ? 0 : 113)*(114*32);
    for (int u = tid; u < 114*32; u += 256) brow[u] = 0;
  }
}

// ---- Kernel 1: fully fused conv3x3 (bf16 MFMA) + IIR ----
// grid (7,14,16). Block = 128 co x 128 pixels (8x16 patch), 4 waves.
// MODE 0: register gather from NCHW f32 (fallback, ws too small).
// MODE 1: global_load_lds direct from padded bf16 x2 (no regs, no pack, the
//   vmcnt drain lands at the barrier only). Linear xs layout (unit u -> 16u B)
//   is the wave-uniform-base + lane*16 pattern; conflicts proven irrelevant
//   (SQ_LDS_BANK_CONFLICT identical across paddings in r2/r3).
// Epilogue split into two 64-t stages: ys 16.9 KB, LDS block 24576 B -> 6 blk/CU.
template<int MODE>
__global__ __launch_bounds__(256, 6) void conv_lif(
    const float* __restrict__ x,
    const unsigned short* __restrict__ x2,
    const unsigned short* __restrict__ Wr,
    const float* __restrict__ bias,
    float* __restrict__ out)
{
  __shared__ unsigned short sm[2*XS_U16];     // 24576 B; ys[128][66] aliases (16896 B)
  const int tid  = threadIdx.x;
  const int lane = tid & 63;
  const int wid  = tid >> 6;         // wave id = co block (32 co each)
  const int l15  = lane & 15;
  const int quad = lane >> 4;
  const int bz = blockIdx.z;
  const int h0 = blockIdx.y * 8, w0 = blockIdx.x * 16;

  const float* xb = x + (size_t)bz * 1605632;             // MODE 0
  const unsigned short* x2b = x2 + (size_t)bz * X2_BZSTR; // MODE 1

  // ---- gather geometry: 720 units (pos 180 x cq 4), <=3 per thread ----
  int  g_off[3], g_ci0[3], g_idx[3];
  bool g_val[3];
  #pragma unroll
  for (int it = 0; it < 3; ++it){
    int u = tid + it*256;
    bool act = (u < 720);
    int uu = act ? u : 0;
    int pos = uu >> 2, cq = uu & 3;
    int row = pos / 18, col = pos - row*18;
    if (MODE == 0){
      int gh = h0 - 1 + row, gw = w0 - 1 + col;
      bool val = act && (gh >= 0) && (gh < 112) && (gw >= 0) && (gw < 112);
      g_off[it] = val ? (gh*112 + gw) : 0;
      g_ci0[it] = cq << 3;
      g_val[it] = val;
      g_idx[it] = 0;
    } else {
      // inactive units read x2b[cic*X2_CICSTR] (safe) into slack slots 720..767
      g_idx[it] = act ? (((h0 + row)*114 + (w0 + col))*32 + (cq << 3)) : 0;
      g_val[it] = act;
      g_off[it] = 0; g_ci0[it] = 0;
    }
  }
  // per-(wave,it) uniform LDS base in u16 units: unit_base*8
  const int ldsb0 = (wid << 6) << 3;          // wid*64*8

  u16x8 g[3];
  #define GATHER_REG(cic_) do{ \
    _Pragma("unroll") \
    for (int it = 0; it < 3; ++it){ \
      const float* p = xb + (size_t)(g_ci0[it] + ((cic_) << 5)) * 12544 + g_off[it]; \
      u16x8 v; \
      _Pragma("unroll") \
      for (int k = 0; k < 8; ++k){ \
        float f = p[(size_t)k * 12544]; \
        f = g_val[it] ? f : 0.0f; \
        v[k] = f2bf(f); \
      } \
      g[it] = v; \
    } }while(0)

  #define WBUF(buf_) do{ \
    unsigned short* xw = sm + (buf_)*XS_U16; \
    _Pragma("unroll") \
    for (int it = 0; it < 3; ++it){ \
      int u = tid + it*256; \
      if (u < 720) *(u16x8*)(xw + u*8) = g[it]; \
    } }while(0)

  #define GATHER_LDS(cic_, buf_) do{ \
    _Pragma("unroll") \
    for (int it = 0; it < 3; ++it){ \
      const unsigned short* srcp = x2b + (size_t)(cic_)*X2_CICSTR + g_idx[it]; \
      __builtin_amdgcn_global_load_lds((gu32*)srcp, \
          (lu32*)(sm + (buf_)*XS_U16 + ldsb0 + it*2048), 16, 0, 0); \
    } }while(0)

  f32x4 acc[2][8];
  #pragma unroll
  for (int i = 0; i < 2; ++i)
    #pragma unroll
    for (int j = 0; j < 8; ++j) acc[i][j] = (f32x4){0.f,0.f,0.f,0.f};

  if (MODE == 1){ GATHER_LDS(0, 0); }
  else          { GATHER_REG(0); WBUF(0); }

  for (int cic = 0; cic < 4; ++cic){
    __syncthreads();                        // xs[cic&1] landed; prev readers done
    const unsigned short* xs = sm + (cic & 1)*XS_U16;
    #pragma unroll
    for (int dw = 0; dw < 3; ++dw){
      // A-frags (L2-resident Wr): af[dh][mt], co = wid*32 + mt*16 + l15
      s16x8 af[3][2];
      #pragma unroll
      for (int dh = 0; dh < 3; ++dh){
        const unsigned short* wp = Wr + ((((dh*3 + dw) << 2) + cic) << 12)
                                      + (((wid << 5) + l15) << 5) + (quad << 3);
        af[dh][0] = *(const s16x8*)wp;
        af[dh][1] = *(const s16x8*)(wp + 512);
      }
      // issue next chunk's LDS-direct gathers AFTER this cic's last A-loads:
      // vmcnt retires in order, so A-frag consumption never waits on gathers.
      if (MODE == 1 && dw == 2 && cic < 3){
        __builtin_amdgcn_sched_barrier(0);
        GATHER_LDS(cic+1, (cic+1) & 1);
      }
      if (MODE == 0 && dw == 1 && cic < 3) GATHER_REG(cic+1);
      // B rows: ring of 6, rows r = nt+dh in [0,10); col = l15+dw, ci = quad*8+
      const unsigned short* bcol = xs + ((l15 + dw) << 5) + (quad << 3);
      s16x8 R[6];
      #pragma unroll
      for (int r = 0; r < 4; ++r) R[r] = *(const s16x8*)(bcol + r*XS_RSTR);
      #pragma unroll
      for (int p = 0; p < 4; ++p){
        if (p < 3){
          R[(2*p+4) % 6] = *(const s16x8*)(bcol + (2*p+4)*XS_RSTR);
          R[(2*p+5) % 6] = *(const s16x8*)(bcol + (2*p+5)*XS_RSTR);
        }
        #pragma unroll
        for (int dh = 0; dh < 3; ++dh){
          #pragma unroll
          for (int sub = 0; sub < 2; ++sub){
            int nt = 2*p + sub;
            s16x8 b = R[(nt + dh) % 6];
            acc[0][nt] = __builtin_amdgcn_mfma_f32_16x16x32_bf16(af[dh][0], b, acc[0][nt], 0, 0, 0);
            acc[1][nt] = __builtin_amdgcn_mfma_f32_16x16x32_bf16(af[dh][1], b, acc[1][nt], 0, 0, 0);
          }
        }
      }
    }
    if (MODE == 0 && cic < 3) WBUF((cic+1) & 1);
  }

  __syncthreads();                          // done with xs; alias as ys (2 stages)
  // C/D layout: col(n=pix)=lane&15, row(m)=quad*4+reg; co = wid*32+mt*16+m
  // IIR state lives across both stages; half 1 warm-starts at t=48.
  {
    int pix  = tid & 127;
    int half = tid >> 7;
    int r = pix >> 4, c = pix & 15;
    float s = 0.f, m = 0.f;
    float* op = out + (size_t)bz*1605632 + (h0 + r)*112 + (w0 + c);
    int t0     = half ? 48 : 0;
    int tstore = half ? 64 : 0;
    int tend   = half ? 128 : 64;

    #pragma unroll
    for (int part = 0; part < 2; ++part){
      if ((wid >> 1) == part){               // waves owning co [part*64, part*64+64)
        #pragma unroll
        for (int mt = 0; mt < 2; ++mt){
          int co = (wid << 5) + (mt << 4) + (quad << 2);
          int cl = co - (part << 6);         // 0..60 within stage
          float4 bv = *(const float4*)(bias + co);
          #pragma unroll
          for (int nt = 0; nt < 8; ++nt){
            int wpix = (nt << 4) + l15;
            f32x4 a = acc[mt][nt];
            ushort2 w01, w23;
            w01.x = f2bf(a.x + bv.x);
            w01.y = f2bf(a.y + bv.y);
            w23.x = f2bf(a.z + bv.z);
            w23.y = f2bf(a.w + bv.w);
            unsigned short* yp = sm + wpix*YS_STRIDE + cl;
            *(ushort2*)(yp)     = w01;
            *(ushort2*)(yp + 2) = w23;
          }
        }
      }
      __syncthreads();                       // ys stage visible
      {
        int lo = t0 > (part << 6) ? t0 : (part << 6);
        int hi = tend < ((part+1) << 6) ? tend : ((part+1) << 6);
        const unsigned short* yr = sm + pix*YS_STRIDE - (part << 6);
        for (int t = lo; t < hi; ++t){
          float y = bf2f(yr[t]);
          s = ALPHA_F * s + y;
          m = BETA_F  * m + OMB_F * s;
          if (t >= tstore) op[(size_t)t*12544] = m;   // 64 B runs along w
        }
      }
      if (part == 0) __syncthreads();        // readers done before stage-1 writers
    }
  }
  #undef GATHER_REG
  #undef GATHER_LDS
  #undef WBUF
}

extern "C" void kernel_launch(void* const* d_in, const int* in_sizes, int n_in,
                              void* d_out, int out_size, void* d_ws, size_t ws_size,
                              hipStream_t stream){
  const float* x = (const float*)d_in[0];
  const float* W = (const float*)d_in[1];
  const float* b = (const float*)d_in[2];
  float* out = (float*)d_out;
  unsigned short* Wr = (unsigned short*)d_ws;    // 294912 B
  reorder_w<<<576, 256, 0, stream>>>(W, Wr);

  const size_t x2_off  = 294912;                          // after Wr, 256-aligned
  const size_t x2_size = (size_t)16 * X2_BZSTR * 2;       // 53,231,616 B
  if (ws_size >= x2_off + x2_size){
    unsigned short* x2 = (unsigned short*)d_ws + x2_off/2;
    convert_x<<<dim3(112, 4, 16), 256, 0, stream>>>(x, x2);
    conv_lif<1><<<dim3(7, 14, 16), 256, 0, stream>>>(x, x2, Wr, b, out);
  } else {
    conv_lif<0><<<dim3(7, 14, 16), 256, 0, stream>>>(x, nullptr, Wr, b, out);
  }
}

// Round 5
// 249.626 us; speedup vs baseline: 1.8222x; 1.8222x over previous
//
#include <hip/hip_runtime.h>

typedef __attribute__((ext_vector_type(8))) short s16x8;            // 8 bf16 (MFMA A/B frag)
typedef __attribute__((ext_vector_type(8))) unsigned short u16x8;   // 16 B vector
typedef __attribute__((ext_vector_type(4))) float f32x4;            // MFMA C/D frag

#define ALPHA_F 0.36787944117144233f
#define BETA_F  0.36787944117144233f
#define OMB_F   0.63212055882855767f   /* 1 - beta */

#define XS_U16   6144   /* one staging buffer: 768 units x 16 B = 12288 B (720 used + 48 slack) */
#define XS_RSTR  576    /* row stride in u16: 18 pos x 32 ci */
#define YS_STRIDE 66    /* epilogue halved: ys[128 pix][66] u16 (64 t + pad), 16896 B */

#define X2_CICSTR 415872u   /* 114*114*32 u16 per (bz,cic) plane */
#define X2_BZSTR  1663488u  /* 4 * X2_CICSTR */

typedef __attribute__((address_space(1))) const unsigned int gu32;
typedef __attribute__((address_space(3))) unsigned int lu32;

__device__ __forceinline__ unsigned short f2bf(float f){
  union { float f; unsigned int u; } v; v.f = f;
  unsigned int u = v.u;
  return (unsigned short)((u + 0x7FFFu + ((u >> 16) & 1u)) >> 16);  // RNE
}
__device__ __forceinline__ float bf2f(unsigned short s){
  union { unsigned int u; float f; } v; v.u = ((unsigned int)s) << 16;
  return v.f;
}

// ---- Kernel 0: W (co,ci,3,3) fp32 -> Wr bf16 [pos9][cic4][co128][cil32] ----
__global__ __launch_bounds__(256) void reorder_w(const float* __restrict__ W,
                                                 unsigned short* __restrict__ Wr){
  int f = blockIdx.x * 256 + threadIdx.x;
  if (f >= 9*128*128) return;
  int cil = f & 31;
  int co  = (f >> 5) & 127;
  int cic = (f >> 12) & 3;
  int pos = f >> 14;
  int ci  = (cic << 5) | cil;
  Wr[f] = f2bf(W[(co*128 + ci)*9 + pos]);
}

// ---- Kernel 0b: x NCHW f32 -> x2[bz][cic][114][114][32] bf16, zero-padded halo.
__global__ __launch_bounds__(256) void convert_x(const float* __restrict__ x,
                                                 unsigned short* __restrict__ x2){
  __shared__ float ls[112*33 + 1];            // ls[w*33 + ci], pad 33 (odd stride)
  const int tid = threadIdx.x;
  const int h = blockIdx.x, cic = blockIdx.y, bz = blockIdx.z;
  const float* src = x + ((size_t)(bz*128 + cic*32))*12544 + (size_t)h*112;
  #pragma unroll
  for (int r = 0; r < 7; ++r){
    int u2 = r*256 + tid;                     // 0..1791 = 32ci * 56 float2
    int ci = u2 / 56, w2 = (u2 - ci*56) << 1;
    float2 v = *(const float2*)(src + (size_t)ci*12544 + w2);
    ls[w2*33 + ci] = v.x;
    ls[(w2+1)*33 + ci] = v.y;
  }
  __syncthreads();
  unsigned short* dst = x2 + (size_t)(bz*4 + cic)*X2_CICSTR + (size_t)(h+1)*(114*32);
  #pragma unroll
  for (int r = 0; r < 7; ++r){
    int u2 = r*256 + tid;                     // 0..1791 = 112pw * 16 pairs
    int pw = u2 >> 4, c2 = (u2 & 15) << 1;
    ushort2 o;
    o.x = f2bf(ls[pw*33 + c2]);
    o.y = f2bf(ls[pw*33 + c2 + 1]);
    *(ushort2*)(dst + (pw+1)*32 + c2) = o;    // contiguous 128 B per wave
  }
  if (tid < 64){
    int cil = tid & 31;
    dst[((tid >> 5) ? 113*32 : 0) + cil] = 0;
  }
  if (h == 0 || h == 111){
    unsigned short* brow = x2 + (size_t)(bz*4 + cic)*X2_CICSTR
                              + (size_t)(h == 0 ? 0 : 113)*(114*32);
    for (int u = tid; u < 114*32; u += 256) brow[u] = 0;
  }
}

// ---- Kernel 1: fully fused conv3x3 (bf16 MFMA) + IIR ----
// grid (7,14,16). Block = 128 co x 128 pixels (8x16 patch), 4 waves.
// MODE 0: register gather from NCHW f32 (fallback, ws too small).
// MODE 1: global_load_lds direct from padded bf16 x2.
// __launch_bounds__(256, 4): live state is 128 arch regs/thread (64 VGPR +
// 64 AGPR acc). (256,6) capped the budget at ~85 and spilled the MFMA
// accumulators to scratch: +680 MB HBM writes, conv 100->293 us (r4). Do not
// raise the wave bid without cutting live regs below 512/waves first.
template<int MODE>
__global__ __launch_bounds__(256, 4) void conv_lif(
    const float* __restrict__ x,
    const unsigned short* __restrict__ x2,
    const unsigned short* __restrict__ Wr,
    const float* __restrict__ bias,
    float* __restrict__ out)
{
  __shared__ unsigned short sm[2*XS_U16];     // 24576 B; ys[128][66] aliases (16896 B)
  const int tid  = threadIdx.x;
  const int lane = tid & 63;
  const int wid  = tid >> 6;         // wave id = co block (32 co each)
  const int l15  = lane & 15;
  const int quad = lane >> 4;
  const int bz = blockIdx.z;
  const int h0 = blockIdx.y * 8, w0 = blockIdx.x * 16;

  const float* xb = x + (size_t)bz * 1605632;             // MODE 0
  const unsigned short* x2b = x2 + (size_t)bz * X2_BZSTR; // MODE 1

  // ---- gather geometry: 720 units (pos 180 x cq 4), <=3 per thread ----
  int  g_off[3], g_ci0[3], g_idx[3];
  bool g_val[3];
  #pragma unroll
  for (int it = 0; it < 3; ++it){
    int u = tid + it*256;
    bool act = (u < 720);
    int uu = act ? u : 0;
    int pos = uu >> 2, cq = uu & 3;
    int row = pos / 18, col = pos - row*18;
    if (MODE == 0){
      int gh = h0 - 1 + row, gw = w0 - 1 + col;
      bool val = act && (gh >= 0) && (gh < 112) && (gw >= 0) && (gw < 112);
      g_off[it] = val ? (gh*112 + gw) : 0;
      g_ci0[it] = cq << 3;
      g_val[it] = val;
      g_idx[it] = 0;
    } else {
      // inactive units read x2b[cic*X2_CICSTR] (safe) into slack slots 720..767
      g_idx[it] = act ? (((h0 + row)*114 + (w0 + col))*32 + (cq << 3)) : 0;
      g_val[it] = act;
      g_off[it] = 0; g_ci0[it] = 0;
    }
  }
  // per-(wave,it) uniform LDS base in u16 units: unit_base*8
  const int ldsb0 = (wid << 6) << 3;          // wid*64*8

  u16x8 g[3];
  #define GATHER_REG(cic_) do{ \
    _Pragma("unroll") \
    for (int it = 0; it < 3; ++it){ \
      const float* p = xb + (size_t)(g_ci0[it] + ((cic_) << 5)) * 12544 + g_off[it]; \
      u16x8 v; \
      _Pragma("unroll") \
      for (int k = 0; k < 8; ++k){ \
        float f = p[(size_t)k * 12544]; \
        f = g_val[it] ? f : 0.0f; \
        v[k] = f2bf(f); \
      } \
      g[it] = v; \
    } }while(0)

  #define WBUF(buf_) do{ \
    unsigned short* xw = sm + (buf_)*XS_U16; \
    _Pragma("unroll") \
    for (int it = 0; it < 3; ++it){ \
      int u = tid + it*256; \
      if (u < 720) *(u16x8*)(xw + u*8) = g[it]; \
    } }while(0)

  #define GATHER_LDS(cic_, buf_) do{ \
    _Pragma("unroll") \
    for (int it = 0; it < 3; ++it){ \
      const unsigned short* srcp = x2b + (size_t)(cic_)*X2_CICSTR + g_idx[it]; \
      __builtin_amdgcn_global_load_lds((gu32*)srcp, \
          (lu32*)(sm + (buf_)*XS_U16 + ldsb0 + it*2048), 16, 0, 0); \
    } }while(0)

  f32x4 acc[2][8];
  #pragma unroll
  for (int i = 0; i < 2; ++i)
    #pragma unroll
    for (int j = 0; j < 8; ++j) acc[i][j] = (f32x4){0.f,0.f,0.f,0.f};

  if (MODE == 1){ GATHER_LDS(0, 0); }
  else          { GATHER_REG(0); WBUF(0); }

  for (int cic = 0; cic < 4; ++cic){
    __syncthreads();                        // xs[cic&1] landed; prev readers done
    const unsigned short* xs = sm + (cic & 1)*XS_U16;
    #pragma unroll
    for (int dw = 0; dw < 3; ++dw){
      // A-frags (L2-resident Wr): af[dh][mt], co = wid*32 + mt*16 + l15
      s16x8 af[3][2];
      #pragma unroll
      for (int dh = 0; dh < 3; ++dh){
        const unsigned short* wp = Wr + ((((dh*3 + dw) << 2) + cic) << 12)
                                      + (((wid << 5) + l15) << 5) + (quad << 3);
        af[dh][0] = *(const s16x8*)wp;
        af[dh][1] = *(const s16x8*)(wp + 512);
      }
      // issue next chunk's LDS-direct gathers AFTER this cic's last A-loads:
      // vmcnt retires in order, so A-frag consumption never waits on gathers.
      if (MODE == 1 && dw == 2 && cic < 3){
        __builtin_amdgcn_sched_barrier(0);
        GATHER_LDS(cic+1, (cic+1) & 1);
      }
      if (MODE == 0 && dw == 1 && cic < 3) GATHER_REG(cic+1);
      // B rows: ring of 6, rows r = nt+dh in [0,10); col = l15+dw, ci = quad*8+
      const unsigned short* bcol = xs + ((l15 + dw) << 5) + (quad << 3);
      s16x8 R[6];
      #pragma unroll
      for (int r = 0; r < 4; ++r) R[r] = *(const s16x8*)(bcol + r*XS_RSTR);
      #pragma unroll
      for (int p = 0; p < 4; ++p){
        if (p < 3){
          R[(2*p+4) % 6] = *(const s16x8*)(bcol + (2*p+4)*XS_RSTR);
          R[(2*p+5) % 6] = *(const s16x8*)(bcol + (2*p+5)*XS_RSTR);
        }
        #pragma unroll
        for (int dh = 0; dh < 3; ++dh){
          #pragma unroll
          for (int sub = 0; sub < 2; ++sub){
            int nt = 2*p + sub;
            s16x8 b = R[(nt + dh) % 6];
            acc[0][nt] = __builtin_amdgcn_mfma_f32_16x16x32_bf16(af[dh][0], b, acc[0][nt], 0, 0, 0);
            acc[1][nt] = __builtin_amdgcn_mfma_f32_16x16x32_bf16(af[dh][1], b, acc[1][nt], 0, 0, 0);
          }
        }
      }
    }
    if (MODE == 0 && cic < 3) WBUF((cic+1) & 1);
  }

  __syncthreads();                          // done with xs; alias as ys (2 stages)
  // C/D layout: col(n=pix)=lane&15, row(m)=quad*4+reg; co = wid*32+mt*16+m
  // IIR state lives across both stages; half 1 warm-starts at t=48.
  {
    int pix  = tid & 127;
    int half = tid >> 7;
    int r = pix >> 4, c = pix & 15;
    float s = 0.f, m = 0.f;
    float* op = out + (size_t)bz*1605632 + (h0 + r)*112 + (w0 + c);
    int t0     = half ? 48 : 0;
    int tstore = half ? 64 : 0;
    int tend   = half ? 128 : 64;

    #pragma unroll
    for (int part = 0; part < 2; ++part){
      if ((wid >> 1) == part){               // waves owning co [part*64, part*64+64)
        #pragma unroll
        for (int mt = 0; mt < 2; ++mt){
          int co = (wid << 5) + (mt << 4) + (quad << 2);
          int cl = co - (part << 6);         // 0..60 within stage
          float4 bv = *(const float4*)(bias + co);
          #pragma unroll
          for (int nt = 0; nt < 8; ++nt){
            int wpix = (nt << 4) + l15;
            f32x4 a = acc[mt][nt];
            ushort2 w01, w23;
            w01.x = f2bf(a.x + bv.x);
            w01.y = f2bf(a.y + bv.y);
            w23.x = f2bf(a.z + bv.z);
            w23.y = f2bf(a.w + bv.w);
            unsigned short* yp = sm + wpix*YS_STRIDE + cl;
            *(ushort2*)(yp)     = w01;
            *(ushort2*)(yp + 2) = w23;
          }
        }
      }
      __syncthreads();                       // ys stage visible
      {
        int lo = t0 > (part << 6) ? t0 : (part << 6);
        int hi = tend < ((part+1) << 6) ? tend : ((part+1) << 6);
        const unsigned short* yr = sm + pix*YS_STRIDE - (part << 6);
        for (int t = lo; t < hi; ++t){
          float y = bf2f(yr[t]);
          s = ALPHA_F * s + y;
          m = BETA_F  * m + OMB_F * s;
          if (t >= tstore) op[(size_t)t*12544] = m;   // 64 B runs along w
        }
      }
      if (part == 0) __syncthreads();        // readers done before stage-1 writers
    }
  }
  #undef GATHER_REG
  #undef GATHER_LDS
  #undef WBUF
}

extern "C" void kernel_launch(void* const* d_in, const int* in_sizes, int n_in,
                              void* d_out, int out_size, void* d_ws, size_t ws_size,
                              hipStream_t stream){
  const float* x = (const float*)d_in[0];
  const float* W = (const float*)d_in[1];
  const float* b = (const float*)d_in[2];
  float* out = (float*)d_out;
  unsigned short* Wr = (unsigned short*)d_ws;    // 294912 B
  reorder_w<<<576, 256, 0, stream>>>(W, Wr);

  const size_t x2_off  = 294912;                          // after Wr, 256-aligned
  const size_t x2_size = (size_t)16 * X2_BZSTR * 2;       // 53,231,616 B
  if (ws_size >= x2_off + x2_size){
    unsigned short* x2 = (unsigned short*)d_ws + x2_off/2;
    convert_x<<<dim3(112, 4, 16), 256, 0, stream>>>(x, x2);
    conv_lif<1><<<dim3(7, 14, 16), 256, 0, stream>>>(x, x2, Wr, b, out);
  } else {
    conv_lif<0><<<dim3(7, 14, 16), 256, 0, stream>>>(x, nullptr, Wr, b, out);
  }
}

// Round 6
// 248.766 us; speedup vs baseline: 1.8285x; 1.0035x over previous
//
#include <hip/hip_runtime.h>

typedef __attribute__((ext_vector_type(8))) short s16x8;            // 8 bf16 (MFMA A/B frag)
typedef __attribute__((ext_vector_type(8))) unsigned short u16x8;   // 16 B vector
typedef __attribute__((ext_vector_type(4))) float f32x4;            // MFMA C/D frag

#define ALPHA_F 0.36787944117144233f
#define BETA_F  0.36787944117144233f
#define OMB_F   0.63212055882855767f   /* 1 - beta */

#define XS_U16   6144   /* one staging buffer: 768 units x 16 B = 12288 B (720 used + 48 slack) */
#define XS_RSTR  576    /* row stride in u16: 18 pos x 32 ci */
#define YS_STRIDE 66    /* epilogue halved: ys[128 pix][66] u16 (64 t + pad), 16896 B */

#define X2_CICSTR 415872u   /* 114*114*32 u16 per (bz,cic) plane */
#define X2_BZSTR  1663488u  /* 4 * X2_CICSTR */

typedef __attribute__((address_space(1))) const unsigned int gu32;
typedef __attribute__((address_space(3))) unsigned int lu32;

__device__ __forceinline__ unsigned short f2bf(float f){
  union { float f; unsigned int u; } v; v.f = f;
  unsigned int u = v.u;
  return (unsigned short)((u + 0x7FFFu + ((u >> 16) & 1u)) >> 16);  // RNE
}
__device__ __forceinline__ float bf2f(unsigned short s){
  union { unsigned int u; float f; } v; v.u = ((unsigned int)s) << 16;
  return v.f;
}

// ---- Kernel 0: W (co,ci,3,3) fp32 -> Wr bf16 [pos9][cic4][co128][cil32] ----
__global__ __launch_bounds__(256) void reorder_w(const float* __restrict__ W,
                                                 unsigned short* __restrict__ Wr){
  int f = blockIdx.x * 256 + threadIdx.x;
  if (f >= 9*128*128) return;
  int cil = f & 31;
  int co  = (f >> 5) & 127;
  int cic = (f >> 12) & 3;
  int pos = f >> 14;
  int ci  = (cic << 5) | cil;
  Wr[f] = f2bf(W[(co*128 + ci)*9 + pos]);
}

// ---- Kernel 0b: x NCHW f32 -> x2[bz][cic][114][114][32] bf16, zero-padded halo.
__global__ __launch_bounds__(256) void convert_x(const float* __restrict__ x,
                                                 unsigned short* __restrict__ x2){
  __shared__ float ls[112*33 + 1];            // ls[w*33 + ci], pad 33 (odd stride)
  const int tid = threadIdx.x;
  const int h = blockIdx.x, cic = blockIdx.y, bz = blockIdx.z;
  const float* src = x + ((size_t)(bz*128 + cic*32))*12544 + (size_t)h*112;
  #pragma unroll
  for (int r = 0; r < 7; ++r){
    int u2 = r*256 + tid;                     // 0..1791 = 32ci * 56 float2
    int ci = u2 / 56, w2 = (u2 - ci*56) << 1;
    float2 v = *(const float2*)(src + (size_t)ci*12544 + w2);
    ls[w2*33 + ci] = v.x;
    ls[(w2+1)*33 + ci] = v.y;
  }
  __syncthreads();
  unsigned short* dst = x2 + (size_t)(bz*4 + cic)*X2_CICSTR + (size_t)(h+1)*(114*32);
  #pragma unroll
  for (int r = 0; r < 7; ++r){
    int u2 = r*256 + tid;                     // 0..1791 = 112pw * 16 pairs
    int pw = u2 >> 4, c2 = (u2 & 15) << 1;
    ushort2 o;
    o.x = f2bf(ls[pw*33 + c2]);
    o.y = f2bf(ls[pw*33 + c2 + 1]);
    *(ushort2*)(dst + (pw+1)*32 + c2) = o;    // contiguous 128 B per wave
  }
  if (tid < 64){
    int cil = tid & 31;
    dst[((tid >> 5) ? 113*32 : 0) + cil] = 0;
  }
  if (h == 0 || h == 111){
    unsigned short* brow = x2 + (size_t)(bz*4 + cic)*X2_CICSTR
                              + (size_t)(h == 0 ? 0 : 113)*(114*32);
    for (int u = tid; u < 114*32; u += 256) brow[u] = 0;
  }
}

// ---- Kernel 1: fully fused conv3x3 (bf16 MFMA) + IIR ----
// grid (7,14,16). Block = 128 co x 128 pixels (8x16 patch), 4 waves.
// MODE 0: register gather from NCHW f32 (fallback, ws too small).
// MODE 1: global_load_lds direct from padded bf16 x2.
// Pipeline (r5): ALL 18 A-frag loads hoisted to cic top (dw-major: dw0
// oldest), THEN the 12 prefetch gathers -> gathers are the newest VMEM ops
// for the whole cic. In-order vmcnt retirement then gives them ~3 dw of
// cover before the barrier drain, and dw1/dw2 A-waits are covered by MFMA.
// Cost: af 24->72 VGPR, total ~176 live regs -> __launch_bounds__(256, 2)
// (256 reg budget, no spill). (256,3)=170 budget would spill; (256,6)
// spilled acc catastrophically in r4 (conv 100->293 us). Check WRITE_SIZE
// ~100 MB == no spill.
template<int MODE>
__global__ __launch_bounds__(256, 2) void conv_lif(
    const float* __restrict__ x,
    const unsigned short* __restrict__ x2,
    const unsigned short* __restrict__ Wr,
    const float* __restrict__ bias,
    float* __restrict__ out)
{
  __shared__ unsigned short sm[2*XS_U16];     // 24576 B; ys[128][66] aliases (16896 B)
  const int tid  = threadIdx.x;
  const int lane = tid & 63;
  const int wid  = tid >> 6;         // wave id = co block (32 co each)
  const int l15  = lane & 15;
  const int quad = lane >> 4;
  const int bz = blockIdx.z;
  const int h0 = blockIdx.y * 8, w0 = blockIdx.x * 16;

  const float* xb = x + (size_t)bz * 1605632;             // MODE 0
  const unsigned short* x2b = x2 + (size_t)bz * X2_BZSTR; // MODE 1

  // ---- gather geometry: 720 units (pos 180 x cq 4), <=3 per thread ----
  int  g_off[3], g_ci0[3], g_idx[3];
  bool g_val[3];
  #pragma unroll
  for (int it = 0; it < 3; ++it){
    int u = tid + it*256;
    bool act = (u < 720);
    int uu = act ? u : 0;
    int pos = uu >> 2, cq = uu & 3;
    int row = pos / 18, col = pos - row*18;
    if (MODE == 0){
      int gh = h0 - 1 + row, gw = w0 - 1 + col;
      bool val = act && (gh >= 0) && (gh < 112) && (gw >= 0) && (gw < 112);
      g_off[it] = val ? (gh*112 + gw) : 0;
      g_ci0[it] = cq << 3;
      g_val[it] = val;
      g_idx[it] = 0;
    } else {
      // inactive units read x2b[cic*X2_CICSTR] (safe) into slack slots 720..767
      g_idx[it] = act ? (((h0 + row)*114 + (w0 + col))*32 + (cq << 3)) : 0;
      g_val[it] = act;
      g_off[it] = 0; g_ci0[it] = 0;
    }
  }
  // per-(wave,it) uniform LDS base in u16 units: unit_base*8
  const int ldsb0 = (wid << 6) << 3;          // wid*64*8

  u16x8 g[3];
  #define GATHER_REG(cic_) do{ \
    _Pragma("unroll") \
    for (int it = 0; it < 3; ++it){ \
      const float* p = xb + (size_t)(g_ci0[it] + ((cic_) << 5)) * 12544 + g_off[it]; \
      u16x8 v; \
      _Pragma("unroll") \
      for (int k = 0; k < 8; ++k){ \
        float f = p[(size_t)k * 12544]; \
        f = g_val[it] ? f : 0.0f; \
        v[k] = f2bf(f); \
      } \
      g[it] = v; \
    } }while(0)

  #define WBUF(buf_) do{ \
    unsigned short* xw = sm + (buf_)*XS_U16; \
    _Pragma("unroll") \
    for (int it = 0; it < 3; ++it){ \
      int u = tid + it*256; \
      if (u < 720) *(u16x8*)(xw + u*8) = g[it]; \
    } }while(0)

  #define GATHER_LDS(cic_, buf_) do{ \
    _Pragma("unroll") \
    for (int it = 0; it < 3; ++it){ \
      const unsigned short* srcp = x2b + (size_t)(cic_)*X2_CICSTR + g_idx[it]; \
      __builtin_amdgcn_global_load_lds((gu32*)srcp, \
          (lu32*)(sm + (buf_)*XS_U16 + ldsb0 + it*2048), 16, 0, 0); \
    } }while(0)

  f32x4 acc[2][8];
  #pragma unroll
  for (int i = 0; i < 2; ++i)
    #pragma unroll
    for (int j = 0; j < 8; ++j) acc[i][j] = (f32x4){0.f,0.f,0.f,0.f};

  if (MODE == 1){ GATHER_LDS(0, 0); }
  else          { GATHER_REG(0); WBUF(0); }

  for (int cic = 0; cic < 4; ++cic){
    __syncthreads();                        // xs[cic&1] landed; prev readers done
    const unsigned short* xs = sm + (cic & 1)*XS_U16;

    // ---- hoisted A-frag loads, dw-major so dw0's retire first ----
    s16x8 af[3][3][2];                      // [dw][dh][mt]
    #pragma unroll
    for (int dw = 0; dw < 3; ++dw){
      #pragma unroll
      for (int dh = 0; dh < 3; ++dh){
        const unsigned short* wp = Wr + ((((dh*3 + dw) << 2) + cic) << 12)
                                      + (((wid << 5) + l15) << 5) + (quad << 3);
        af[dw][dh][0] = *(const s16x8*)wp;
        af[dw][dh][1] = *(const s16x8*)(wp + 512);
      }
      __builtin_amdgcn_sched_barrier(0);    // pin dw-major issue order
    }
    // prefetch gathers are now the NEWEST VMEM ops for this whole cic:
    // no A-frag wait retires them; the only drain is next cic's barrier,
    // a full ~3-dw MFMA span away.
    if (MODE == 1 && cic < 3){
      GATHER_LDS(cic+1, (cic+1) & 1);
      __builtin_amdgcn_sched_barrier(0);
    }

    #pragma unroll
    for (int dw = 0; dw < 3; ++dw){
      if (MODE == 0 && dw == 1 && cic < 3) GATHER_REG(cic+1);
      // B rows: ring of 6, rows r = nt+dh in [0,10); col = l15+dw, ci = quad*8+
      const unsigned short* bcol = xs + ((l15 + dw) << 5) + (quad << 3);
      s16x8 R[6];
      #pragma unroll
      for (int r = 0; r < 4; ++r) R[r] = *(const s16x8*)(bcol + r*XS_RSTR);
      #pragma unroll
      for (int p = 0; p < 4; ++p){
        if (p < 3){
          R[(2*p+4) % 6] = *(const s16x8*)(bcol + (2*p+4)*XS_RSTR);
          R[(2*p+5) % 6] = *(const s16x8*)(bcol + (2*p+5)*XS_RSTR);
        }
        #pragma unroll
        for (int dh = 0; dh < 3; ++dh){
          #pragma unroll
          for (int sub = 0; sub < 2; ++sub){
            int nt = 2*p + sub;
            s16x8 b = R[(nt + dh) % 6];
            acc[0][nt] = __builtin_amdgcn_mfma_f32_16x16x32_bf16(af[dw][dh][0], b, acc[0][nt], 0, 0, 0);
            acc[1][nt] = __builtin_amdgcn_mfma_f32_16x16x32_bf16(af[dw][dh][1], b, acc[1][nt], 0, 0, 0);
          }
        }
      }
    }
    if (MODE == 0 && cic < 3) WBUF((cic+1) & 1);
  }

  __syncthreads();                          // done with xs; alias as ys (2 stages)
  // C/D layout: col(n=pix)=lane&15, row(m)=quad*4+reg; co = wid*32+mt*16+m
  // IIR state lives across both stages; half 1 warm-starts at t=48.
  {
    int pix  = tid & 127;
    int half = tid >> 7;
    int r = pix >> 4, c = pix & 15;
    float s = 0.f, m = 0.f;
    float* op = out + (size_t)bz*1605632 + (h0 + r)*112 + (w0 + c);
    int t0     = half ? 48 : 0;
    int tstore = half ? 64 : 0;
    int tend   = half ? 128 : 64;

    #pragma unroll
    for (int part = 0; part < 2; ++part){
      if ((wid >> 1) == part){               // waves owning co [part*64, part*64+64)
        #pragma unroll
        for (int mt = 0; mt < 2; ++mt){
          int co = (wid << 5) + (mt << 4) + (quad << 2);
          int cl = co - (part << 6);         // 0..60 within stage
          float4 bv = *(const float4*)(bias + co);
          #pragma unroll
          for (int nt = 0; nt < 8; ++nt){
            int wpix = (nt << 4) + l15;
            f32x4 a = acc[mt][nt];
            ushort2 w01, w23;
            w01.x = f2bf(a.x + bv.x);
            w01.y = f2bf(a.y + bv.y);
            w23.x = f2bf(a.z + bv.z);
            w23.y = f2bf(a.w + bv.w);
            unsigned short* yp = sm + wpix*YS_STRIDE + cl;
            *(ushort2*)(yp)     = w01;
            *(ushort2*)(yp + 2) = w23;
          }
        }
      }
      __syncthreads();                       // ys stage visible
      {
        int lo = t0 > (part << 6) ? t0 : (part << 6);
        int hi = tend < ((part+1) << 6) ? tend : ((part+1) << 6);
        const unsigned short* yr = sm + pix*YS_STRIDE - (part << 6);
        for (int t = lo; t < hi; ++t){
          float y = bf2f(yr[t]);
          s = ALPHA_F * s + y;
          m = BETA_F  * m + OMB_F * s;
          if (t >= tstore) op[(size_t)t*12544] = m;   // 64 B runs along w
        }
      }
      if (part == 0) __syncthreads();        // readers done before stage-1 writers
    }
  }
  #undef GATHER_REG
  #undef GATHER_LDS
  #undef WBUF
}

extern "C" void kernel_launch(void* const* d_in, const int* in_sizes, int n_in,
                              void* d_out, int out_size, void* d_ws, size_t ws_size,
                              hipStream_t stream){
  const float* x = (const float*)d_in[0];
  const float* W = (const float*)d_in[1];
  const float* b = (const float*)d_in[2];
  float* out = (float*)d_out;
  unsigned short* Wr = (unsigned short*)d_ws;    // 294912 B
  reorder_w<<<576, 256, 0, stream>>>(W, Wr);

  const size_t x2_off  = 294912;                          // after Wr, 256-aligned
  const size_t x2_size = (size_t)16 * X2_BZSTR * 2;       // 53,231,616 B
  if (ws_size >= x2_off + x2_size){
    unsigned short* x2 = (unsigned short*)d_ws + x2_off/2;
    convert_x<<<dim3(112, 4, 16), 256, 0, stream>>>(x, x2);
    conv_lif<1><<<dim3(7, 14, 16), 256, 0, stream>>>(x, x2, Wr, b, out);
  } else {
    conv_lif<0><<<dim3(7, 14, 16), 256, 0, stream>>>(x, nullptr, Wr, b, out);
  }
}

// Round 12
// 244.771 us; speedup vs baseline: 1.8583x; 1.0163x over previous
//
#include <hip/hip_runtime.h>

typedef __attribute__((ext_vector_type(8))) short s16x8;            // 8 bf16 (MFMA A/B frag)
typedef __attribute__((ext_vector_type(8))) unsigned short u16x8;   // 16 B vector
typedef __attribute__((ext_vector_type(4))) float f32x4;            // MFMA C/D frag

#define ALPHA_F 0.36787944117144233f
#define BETA_F  0.36787944117144233f
#define OMB_F   0.63212055882855767f   /* 1 - beta */

#define XS_U16   6144   /* one staging buffer: 768 units x 16 B = 12288 B (720 used + 48 slack) */
#define XS_RSTR  576    /* row stride in u16: 18 pos x 32 ci */
#define YS_STRIDE 88    /* epilogue row: 88 u16 = 176 B -> 16B-aligned rows for b128 reads; */
                        /* 176 mod 128 = 48 -> 8 distinct phases/16 lanes -> <=2-way (free). */
                        /* ys = 128*88*2 = 22528 B <= 24576 B xs alias. */

#define X2_CICSTR 415872u   /* 114*114*32 u16 per (bz,cic) plane */
#define X2_BZSTR  1663488u  /* 4 * X2_CICSTR */

typedef __attribute__((address_space(1))) const unsigned int gu32;
typedef __attribute__((address_space(3))) unsigned int lu32;

__device__ __forceinline__ unsigned short f2bf(float f){
  union { float f; unsigned int u; } v; v.f = f;
  unsigned int u = v.u;
  return (unsigned short)((u + 0x7FFFu + ((u >> 16) & 1u)) >> 16);  // RNE
}
__device__ __forceinline__ float bf2f(unsigned short s){
  union { unsigned int u; float f; } v; v.u = ((unsigned int)s) << 16;
  return v.f;
}

// ---- Kernel 0: W (co,ci,3,3) fp32 -> Wr bf16 [pos9][cic4][co128][cil32] ----
__global__ __launch_bounds__(256) void reorder_w(const float* __restrict__ W,
                                                 unsigned short* __restrict__ Wr){
  int f = blockIdx.x * 256 + threadIdx.x;
  if (f >= 9*128*128) return;
  int cil = f & 31;
  int co  = (f >> 5) & 127;
  int cic = (f >> 12) & 3;
  int pos = f >> 14;
  int ci  = (cic << 5) | cil;
  Wr[f] = f2bf(W[(co*128 + ci)*9 + pos]);
}

// ---- Kernel 0b: x NCHW f32 -> x2[bz][cic][114][114][32] bf16, zero-padded halo.
__global__ __launch_bounds__(256) void convert_x(const float* __restrict__ x,
                                                 unsigned short* __restrict__ x2){
  __shared__ float ls[112*33 + 1];            // ls[w*33 + ci], pad 33 (odd stride)
  const int tid = threadIdx.x;
  const int h = blockIdx.x, cic = blockIdx.y, bz = blockIdx.z;
  const float* src = x + ((size_t)(bz*128 + cic*32))*12544 + (size_t)h*112;
  #pragma unroll
  for (int r = 0; r < 7; ++r){
    int u2 = r*256 + tid;                     // 0..1791 = 32ci * 56 float2
    int ci = u2 / 56, w2 = (u2 - ci*56) << 1;
    float2 v = *(const float2*)(src + (size_t)ci*12544 + w2);
    ls[w2*33 + ci] = v.x;
    ls[(w2+1)*33 + ci] = v.y;
  }
  __syncthreads();
  unsigned short* dst = x2 + (size_t)(bz*4 + cic)*X2_CICSTR + (size_t)(h+1)*(114*32);
  #pragma unroll
  for (int r = 0; r < 7; ++r){
    int u2 = r*256 + tid;                     // 0..1791 = 112pw * 16 pairs
    int pw = u2 >> 4, c2 = (u2 & 15) << 1;
    ushort2 o;
    o.x = f2bf(ls[pw*33 + c2]);
    o.y = f2bf(ls[pw*33 + c2 + 1]);
    *(ushort2*)(dst + (pw+1)*32 + c2) = o;    // contiguous 128 B per wave
  }
  if (tid < 64){
    int cil = tid & 31;
    dst[((tid >> 5) ? 113*32 : 0) + cil] = 0;
  }
  if (h == 0 || h == 111){
    unsigned short* brow = x2 + (size_t)(bz*4 + cic)*X2_CICSTR
                              + (size_t)(h == 0 ? 0 : 113)*(114*32);
    for (int u = tid; u < 114*32; u += 256) brow[u] = 0;
  }
}

// ---- Kernel 1: fully fused conv3x3 (bf16 MFMA) + IIR ----
// grid (7,14,16). Block = 128 co x 128 pixels (8x16 patch), 4 waves.
// MODE 0: register gather from NCHW f32 (fallback, ws too small).
// MODE 1: global_load_lds direct from padded bf16 x2, prefetch issued at
//   dw==2 (newest in VMEM queue; ~1 dw of MFMA cover suffices — r5/r6 A/B
//   showed the K-loop is not VMEM-latency-limited).
// __launch_bounds__(256, 4): 64 VGPR + 64 AGPR = 128 unified regs -> 16
// waves/CU. (256,6) spilled acc catastrophically (r4: conv 293 us); the r6
// full-hoist variant needed (256,2) and regressed. Keep (256,4).
template<int MODE>
__global__ __launch_bounds__(256, 4) void conv_lif(
    const float* __restrict__ x,
    const unsigned short* __restrict__ x2,
    const unsigned short* __restrict__ Wr,
    const float* __restrict__ bias,
    float* __restrict__ out)
{
  __shared__ unsigned short sm[2*XS_U16];     // 24576 B; ys[128][88] aliases (22528 B)
  const int tid  = threadIdx.x;
  const int lane = tid & 63;
  const int wid  = tid >> 6;         // wave id = co block (32 co each)
  const int l15  = lane & 15;
  const int quad = lane >> 4;
  const int bz = blockIdx.z;
  const int h0 = blockIdx.y * 8, w0 = blockIdx.x * 16;

  const float* xb = x + (size_t)bz * 1605632;             // MODE 0
  const unsigned short* x2b = x2 + (size_t)bz * X2_BZSTR; // MODE 1

  // ---- gather geometry: 720 units (pos 180 x cq 4), <=3 per thread ----
  int  g_off[3], g_ci0[3], g_idx[3];
  bool g_val[3];
  #pragma unroll
  for (int it = 0; it < 3; ++it){
    int u = tid + it*256;
    bool act = (u < 720);
    int uu = act ? u : 0;
    int pos = uu >> 2, cq = uu & 3;
    int row = pos / 18, col = pos - row*18;
    if (MODE == 0){
      int gh = h0 - 1 + row, gw = w0 - 1 + col;
      bool val = act && (gh >= 0) && (gh < 112) && (gw >= 0) && (gw < 112);
      g_off[it] = val ? (gh*112 + gw) : 0;
      g_ci0[it] = cq << 3;
      g_val[it] = val;
      g_idx[it] = 0;
    } else {
      // inactive units read x2b[cic*X2_CICSTR] (safe) into slack slots 720..767
      g_idx[it] = act ? (((h0 + row)*114 + (w0 + col))*32 + (cq << 3)) : 0;
      g_val[it] = act;
      g_off[it] = 0; g_ci0[it] = 0;
    }
  }
  // per-(wave,it) uniform LDS base in u16 units: unit_base*8
  const int ldsb0 = (wid << 6) << 3;          // wid*64*8

  u16x8 g[3];
  #define GATHER_REG(cic_) do{ \
    _Pragma("unroll") \
    for (int it = 0; it < 3; ++it){ \
      const float* p = xb + (size_t)(g_ci0[it] + ((cic_) << 5)) * 12544 + g_off[it]; \
      u16x8 v; \
      _Pragma("unroll") \
      for (int k = 0; k < 8; ++k){ \
        float f = p[(size_t)k * 12544]; \
        f = g_val[it] ? f : 0.0f; \
        v[k] = f2bf(f); \
      } \
      g[it] = v; \
    } }while(0)

  #define WBUF(buf_) do{ \
    unsigned short* xw = sm + (buf_)*XS_U16; \
    _Pragma("unroll") \
    for (int it = 0; it < 3; ++it){ \
      int u = tid + it*256; \
      if (u < 720) *(u16x8*)(xw + u*8) = g[it]; \
    } }while(0)

  #define GATHER_LDS(cic_, buf_) do{ \
    _Pragma("unroll") \
    for (int it = 0; it < 3; ++it){ \
      const unsigned short* srcp = x2b + (size_t)(cic_)*X2_CICSTR + g_idx[it]; \
      __builtin_amdgcn_global_load_lds((gu32*)srcp, \
          (lu32*)(sm + (buf_)*XS_U16 + ldsb0 + it*2048), 16, 0, 0); \
    } }while(0)

  f32x4 acc[2][8];
  #pragma unroll
  for (int i = 0; i < 2; ++i)
    #pragma unroll
    for (int j = 0; j < 8; ++j) acc[i][j] = (f32x4){0.f,0.f,0.f,0.f};

  if (MODE == 1){ GATHER_LDS(0, 0); }
  else          { GATHER_REG(0); WBUF(0); }

  for (int cic = 0; cic < 4; ++cic){
    __syncthreads();                        // xs[cic&1] landed; prev readers done
    const unsigned short* xs = sm + (cic & 1)*XS_U16;
    #pragma unroll
    for (int dw = 0; dw < 3; ++dw){
      // A-frags (L2-resident Wr): af[dh][mt], co = wid*32 + mt*16 + l15
      s16x8 af[3][2];
      #pragma unroll
      for (int dh = 0; dh < 3; ++dh){
        const unsigned short* wp = Wr + ((((dh*3 + dw) << 2) + cic) << 12)
                                      + (((wid << 5) + l15) << 5) + (quad << 3);
        af[dh][0] = *(const s16x8*)wp;
        af[dh][1] = *(const s16x8*)(wp + 512);
      }
      // issue next chunk's LDS-direct gathers AFTER this cic's last A-loads:
      // vmcnt retires in order, so A-frag consumption never waits on gathers.
      if (MODE == 1 && dw == 2 && cic < 3){
        __builtin_amdgcn_sched_barrier(0);
        GATHER_LDS(cic+1, (cic+1) & 1);
      }
      if (MODE == 0 && dw == 1 && cic < 3) GATHER_REG(cic+1);
      // B rows: ring of 6, rows r = nt+dh in [0,10); col = l15+dw, ci = quad*8+
      const unsigned short* bcol = xs + ((l15 + dw) << 5) + (quad << 3);
      s16x8 R[6];
      #pragma unroll
      for (int r = 0; r < 4; ++r) R[r] = *(const s16x8*)(bcol + r*XS_RSTR);
      #pragma unroll
      for (int p = 0; p < 4; ++p){
        if (p < 3){
          R[(2*p+4) % 6] = *(const s16x8*)(bcol + (2*p+4)*XS_RSTR);
          R[(2*p+5) % 6] = *(const s16x8*)(bcol + (2*p+5)*XS_RSTR);
        }
        #pragma unroll
        for (int dh = 0; dh < 3; ++dh){
          #pragma unroll
          for (int sub = 0; sub < 2; ++sub){
            int nt = 2*p + sub;
            s16x8 b = R[(nt + dh) % 6];
            acc[0][nt] = __builtin_amdgcn_mfma_f32_16x16x32_bf16(af[dh][0], b, acc[0][nt], 0, 0, 0);
            acc[1][nt] = __builtin_amdgcn_mfma_f32_16x16x32_bf16(af[dh][1], b, acc[1][nt], 0, 0, 0);
          }
        }
      }
    }
    if (MODE == 0 && cic < 3) WBUF((cic+1) & 1);
  }

  __syncthreads();                          // done with xs; alias as ys (2 stages)
  // C/D layout: col(n=pix)=lane&15, row(m)=quad*4+reg; co = wid*32+mt*16+m
  // IIR state lives across both stages; half 1 warm-starts at t=48.
  // Epilogue reads vectorized: u16x8 = 8 t per ds_read_b128 (was 80 scalar
  // ds_read_u16/thread); store predicate uniform per 8-block (t0/tstore %8==0).
  {
    int pix  = tid & 127;
    int half = tid >> 7;
    int r = pix >> 4, c = pix & 15;
    float s = 0.f, m = 0.f;
    float* op = out + (size_t)bz*1605632 + (h0 + r)*112 + (w0 + c);
    int t0     = half ? 48 : 0;
    int tstore = half ? 64 : 0;
    int tend   = half ? 128 : 64;

    #pragma unroll
    for (int part = 0; part < 2; ++part){
      if ((wid >> 1) == part){               // waves owning co [part*64, part*64+64)
        #pragma unroll
        for (int mt = 0; mt < 2; ++mt){
          int co = (wid << 5) + (mt << 4) + (quad << 2);
          int cl = co - (part << 6);         // 0..60 within stage
          float4 bv = *(const float4*)(bias + co);
          #pragma unroll
          for (int nt = 0; nt < 8; ++nt){
            int wpix = (nt << 4) + l15;
            f32x4 a = acc[mt][nt];
            ushort2 w01, w23;
            w01.x = f2bf(a.x + bv.x);
            w01.y = f2bf(a.y + bv.y);
            w23.x = f2bf(a.z + bv.z);
            w23.y = f2bf(a.w + bv.w);
            unsigned short* yp = sm + wpix*YS_STRIDE + cl;
            *(ushort2*)(yp)     = w01;
            *(ushort2*)(yp + 2) = w23;
          }
        }
      }
      __syncthreads();                       // ys stage visible
      {
        int lo = t0 > (part << 6) ? t0 : (part << 6);
        int hi = tend < ((part+1) << 6) ? tend : ((part+1) << 6);
        const unsigned short* yr = sm + pix*YS_STRIDE - (part << 6);
        for (int tb = lo; tb < hi; tb += 8){
          u16x8 yv = *(const u16x8*)(yr + tb);     // (tb - part*64) u16 offset, 16B-aligned
          bool st = (tb >= tstore);                // uniform per 8-block
          #pragma unroll
          for (int k = 0; k < 8; ++k){
            float y = bf2f(yv[k]);
            s = ALPHA_F * s + y;
            m = BETA_F  * m + OMB_F * s;
            if (st) op[(size_t)(tb + k)*12544] = m;   // 64 B runs along w
          }
        }
      }
      if (part == 0) __syncthreads();        // readers done before stage-1 writers
    }
  }
  #undef GATHER_REG
  #undef GATHER_LDS
  #undef WBUF
}

extern "C" void kernel_launch(void* const* d_in, const int* in_sizes, int n_in,
                              void* d_out, int out_size, void* d_ws, size_t ws_size,
                              hipStream_t stream){
  const float* x = (const float*)d_in[0];
  const float* W = (const float*)d_in[1];
  const float* b = (const float*)d_in[2];
  float* out = (float*)d_out;
  unsigned short* Wr = (unsigned short*)d_ws;    // 294912 B
  reorder_w<<<576, 256, 0, stream>>>(W, Wr);

  const size_t x2_off  = 294912;                          // after Wr, 256-aligned
  const size_t x2_size = (size_t)16 * X2_BZSTR * 2;       // 53,231,616 B
  if (ws_size >= x2_off + x2_size){
    unsigned short* x2 = (unsigned short*)d_ws + x2_off/2;
    convert_x<<<dim3(112, 4, 16), 256, 0, stream>>>(x, x2);
    conv_lif<1><<<dim3(7, 14, 16), 256, 0, stream>>>(x, x2, Wr, b, out);
  } else {
    conv_lif<0><<<dim3(7, 14, 16), 256, 0, stream>>>(x, nullptr, Wr, b, out);
  }
}